// Round 1
// baseline (56.768 us; speedup 1.0000x reference)
//
#include <hip/hip_runtime.h>
#include <hip/hip_bf16.h>

typedef __attribute__((ext_vector_type(8))) short bf16x8;
typedef __attribute__((ext_vector_type(4))) float f32x4;

#define NB   4
#define NN   2048
#define FIN  256
#define FOUT 128

__device__ __forceinline__ unsigned short f2bf(float f) {
    unsigned int u = __builtin_bit_cast(unsigned int, f);
    u += 0x7fffu + ((u >> 16) & 1u);
    return (unsigned short)(u >> 16);
}

// ---------------- Kernel 0: WT[o][k] bf16 from W[k][o] f32 ----------------
__global__ __launch_bounds__(256) void k_wt(const float* __restrict__ W,
                                            unsigned short* __restrict__ WT) {
    int idx = blockIdx.x * 256 + threadIdx.x;      // 32768 = 128*256
    int k = idx & 255, o = idx >> 8;
    WT[idx] = f2bf(W[k * FOUT + o]);
}

// ---------------- Kernel 1: Wh = h@W (MFMA), writes WhT bf16 + s1,s2 ------
__global__ __launch_bounds__(256) void k_wh(const float* __restrict__ h,
                                            const float* __restrict__ a,
                                            const unsigned short* __restrict__ WT,
                                            unsigned short* __restrict__ WhT,
                                            float* __restrict__ s1,
                                            float* __restrict__ s2) {
    __shared__ unsigned short hs[64][264];         // 64 rows x 256 bf16, pad 8
    int t = threadIdx.x, blk = blockIdx.x;

    // stage 64 rows of h as bf16 into LDS
    const float4* h4 = (const float4*)h + (size_t)blk * 4096;
    #pragma unroll
    for (int i = 0; i < 16; ++i) {
        int idx = i * 256 + t;                     // float4 index within tile
        float4 v = h4[idx];
        int row = idx >> 6, c4 = (idx & 63) * 4;
        unsigned int lo = (unsigned int)f2bf(v.x) | ((unsigned int)f2bf(v.y) << 16);
        unsigned int hi = (unsigned int)f2bf(v.z) | ((unsigned int)f2bf(v.w) << 16);
        *(uint2*)&hs[row][c4] = make_uint2(lo, hi);
    }
    __syncthreads();

    int w = t >> 6, l = t & 63, lr = l & 15, lk = l >> 4;
    float a1v[8], a2v[8];
    #pragma unroll
    for (int ot = 0; ot < 8; ++ot) {
        a1v[ot] = a[ot * 16 + lr];
        a2v[ot] = a[FOUT + ot * 16 + lr];
    }
    f32x4 acc[8];
    #pragma unroll
    for (int ot = 0; ot < 8; ++ot) acc[ot] = (f32x4){0.f, 0.f, 0.f, 0.f};

    #pragma unroll
    for (int kk = 0; kk < 8; ++kk) {
        int k0 = kk * 32;
        bf16x8 af = *(const bf16x8*)&hs[w * 16 + lr][k0 + lk * 8];
        #pragma unroll
        for (int ot = 0; ot < 8; ++ot) {
            bf16x8 bf = *(const bf16x8*)(WT + (ot * 16 + lr) * 256 + k0 + lk * 8);
            acc[ot] = __builtin_amdgcn_mfma_f32_16x16x32_bf16(af, bf, acc[ot], 0, 0, 0);
        }
    }

    // epilogue: write WhT bf16 (transposed) and s1/s2
    int nglob0 = blk * 64 + w * 16;                // wave's 16-row tile base
    int b = nglob0 >> 11;
    int nn0 = (nglob0 & 2047) + lk * 4;
    float v1[4] = {0.f, 0.f, 0.f, 0.f}, v2[4] = {0.f, 0.f, 0.f, 0.f};
    #pragma unroll
    for (int ot = 0; ot < 8; ++ot) {
        float x0 = acc[ot][0], x1 = acc[ot][1], x2 = acc[ot][2], x3 = acc[ot][3];
        ushort4 pk;
        pk.x = f2bf(x0); pk.y = f2bf(x1); pk.z = f2bf(x2); pk.w = f2bf(x3);
        *(ushort4*)(WhT + (size_t)(b * FOUT + ot * 16 + lr) * NN + nn0) = pk;
        v1[0] += x0 * a1v[ot]; v1[1] += x1 * a1v[ot]; v1[2] += x2 * a1v[ot]; v1[3] += x3 * a1v[ot];
        v2[0] += x0 * a2v[ot]; v2[1] += x1 * a2v[ot]; v2[2] += x2 * a2v[ot]; v2[3] += x3 * a2v[ot];
    }
    #pragma unroll
    for (int m = 1; m < 16; m <<= 1) {
        #pragma unroll
        for (int r = 0; r < 4; ++r) {
            v1[r] += __shfl_xor(v1[r], m);
            v2[r] += __shfl_xor(v2[r], m);
        }
    }
    if (lr == 0) {
        int n = nglob0 + lk * 4;
        *(float4*)(s1 + n) = make_float4(v1[0], v1[1], v1[2], v1[3]);
        *(float4*)(s2 + n) = make_float4(v2[0], v2[1], v2[2], v2[3]);
    }
}

// ---------------- Kernel 2: fused attention + LayerNorm + GELU ------------
__global__ __launch_bounds__(256) void k_attn(const int* __restrict__ adj,
                                              const unsigned short* __restrict__ WhT,
                                              const float* __restrict__ s1,
                                              const float* __restrict__ s2,
                                              const float* __restrict__ gamma,
                                              const float* __restrict__ beta,
                                              float* __restrict__ out) {
    __shared__ unsigned short Ps[2][16][72];       // P tile bf16, 2 slots, pad 72
    __shared__ float ZS[16];
    __shared__ float hS[16][132];

    int t = threadIdx.x, w = t >> 6, l = t & 63, lr = l & 15, lk = l >> 4;
    int bi = blockIdx.x, b = bi >> 7, i0 = (bi & 127) * 16;
    int rowA = t >> 4, kA = (t & 15) * 4;

    const int*   adjp = adj + (size_t)(b * NN + i0 + rowA) * NN + kA;
    const float* s2p  = s2 + b * NN + kA;
    float s1r = s1[b * NN + i0 + rowA];

    int obase = w * 32;
    const unsigned short* Bb = WhT + (size_t)(b * FOUT + obase + lr) * NN + lk * 8;

    f32x4 acc0 = {0.f, 0.f, 0.f, 0.f}, acc1 = {0.f, 0.f, 0.f, 0.f};
    float zacc = 0.f;

    // software prefetch of step 0
    int4   av = *(const int4*)adjp;
    float4 sv = *(const float4*)s2p;
    bf16x8 nb00 = *(const bf16x8*)(Bb);
    bf16x8 nb01 = *(const bf16x8*)(Bb + 32);
    bf16x8 nb10 = *(const bf16x8*)(Bb + 16 * NN);
    bf16x8 nb11 = *(const bf16x8*)(Bb + 16 * NN + 32);

    for (int step = 0; step < 32; ++step) {
        int slot = step & 1;
        int4 avc = av; float4 svc = sv;
        bf16x8 b00 = nb00, b01 = nb01, b10 = nb10, b11 = nb11;
        if (step < 31) {                           // uniform branch
            adjp += 64; s2p += 64;
            av = *(const int4*)adjp;
            sv = *(const float4*)s2p;
            const unsigned short* Bn = Bb + (step + 1) * 64;
            nb00 = *(const bf16x8*)(Bn);
            nb01 = *(const bf16x8*)(Bn + 32);
            nb10 = *(const bf16x8*)(Bn + 16 * NN);
            nb11 = *(const bf16x8*)(Bn + 16 * NN + 32);
        }

        // ---- phase A: build P tile (16 x 64) in bf16 ----
        {
            int   am[4] = {avc.x, avc.y, avc.z, avc.w};
            float ss[4] = {svc.x, svc.y, svc.z, svc.w};
            unsigned short u[4];
            #pragma unroll
            for (int i = 0; i < 4; ++i) {
                float tt  = s1r + ss[i];
                float lrl = fmaxf(tt, 0.2f * tt);  // LeakyReLU
                float pp  = (am[i] > 0) ? __expf(lrl) : 0.f;
                zacc += pp;
                u[i] = f2bf(pp);
            }
            unsigned int lo = (unsigned int)u[0] | ((unsigned int)u[1] << 16);
            unsigned int hi = (unsigned int)u[2] | ((unsigned int)u[3] << 16);
            *(uint2*)&Ps[slot][rowA][kA] = make_uint2(lo, hi);
        }
        __syncthreads();

        // ---- phase B: 4 MFMAs ----
        const unsigned short* pr = &Ps[slot][lr][lk * 8];
        bf16x8 a0 = *(const bf16x8*)pr;
        bf16x8 a1 = *(const bf16x8*)(pr + 32);
        acc0 = __builtin_amdgcn_mfma_f32_16x16x32_bf16(a0, b00, acc0, 0, 0, 0);
        acc0 = __builtin_amdgcn_mfma_f32_16x16x32_bf16(a1, b01, acc0, 0, 0, 0);
        acc1 = __builtin_amdgcn_mfma_f32_16x16x32_bf16(a0, b10, acc1, 0, 0, 0);
        acc1 = __builtin_amdgcn_mfma_f32_16x16x32_bf16(a1, b11, acc1, 0, 0, 0);
    }

    // ---- Z reduction (16 lanes per row) ----
    #pragma unroll
    for (int m = 1; m < 16; m <<= 1) zacc += __shfl_xor(zacc, m);
    if ((t & 15) == 0) ZS[rowA] = zacc;
    __syncthreads();

    // ---- divide by Z, stage h' in LDS ----
    #pragma unroll
    for (int r = 0; r < 4; ++r) {
        int row = lk * 4 + r;
        float rz = 1.f / ZS[row];
        hS[row][obase + lr]      = acc0[r] * rz;
        hS[row][obase + 16 + lr] = acc1[r] * rz;
    }
    __syncthreads();

    // ---- LayerNorm + exact GELU, write out ----
    int c0 = (t & 15) * 8;
    float x[8];
    *(float4*)&x[0] = *(const float4*)&hS[rowA][c0];
    *(float4*)&x[4] = *(const float4*)&hS[rowA][c0 + 4];
    float sm = 0.f, sq = 0.f;
    #pragma unroll
    for (int i = 0; i < 8; ++i) { sm += x[i]; sq += x[i] * x[i]; }
    #pragma unroll
    for (int m = 1; m < 16; m <<= 1) {
        sm += __shfl_xor(sm, m);
        sq += __shfl_xor(sq, m);
    }
    float mu  = sm * (1.f / 128.f);
    float var = sq * (1.f / 128.f) - mu * mu;
    float rs  = rsqrtf(var + 1e-5f);
    float4 g0 = *(const float4*)(gamma + c0);
    float4 g1 = *(const float4*)(gamma + c0 + 4);
    float4 e0 = *(const float4*)(beta + c0);
    float4 e1 = *(const float4*)(beta + c0 + 4);
    float gg[8] = {g0.x, g0.y, g0.z, g0.w, g1.x, g1.y, g1.z, g1.w};
    float bb[8] = {e0.x, e0.y, e0.z, e0.w, e1.x, e1.y, e1.z, e1.w};
    float y[8];
    #pragma unroll
    for (int i = 0; i < 8; ++i) {
        float v = (x[i] - mu) * rs * gg[i] + bb[i];
        y[i] = 0.5f * v * (1.f + erff(v * 0.70710678118f));
    }
    float* op = out + (size_t)(b * NN + i0 + rowA) * FOUT + c0;
    *(float4*)op       = make_float4(y[0], y[1], y[2], y[3]);
    *(float4*)(op + 4) = make_float4(y[4], y[5], y[6], y[7]);
}

// ---------------- launcher ----------------
extern "C" void kernel_launch(void* const* d_in, const int* in_sizes, int n_in,
                              void* d_out, int out_size, void* d_ws, size_t ws_size,
                              hipStream_t stream) {
    const float* h     = (const float*)d_in[0];
    const int*   adj   = (const int*)d_in[1];
    const float* W     = (const float*)d_in[2];
    const float* a     = (const float*)d_in[3];
    const float* gamma = (const float*)d_in[4];
    const float* beta  = (const float*)d_in[5];
    float* out = (float*)d_out;

    char* ws = (char*)d_ws;
    unsigned short* WT  = (unsigned short*)ws;                       // 64 KiB
    unsigned short* WhT = (unsigned short*)(ws + 65536);             // 2 MiB
    float* s1 = (float*)(ws + 65536 + 2097152);                      // 32 KiB
    float* s2 = (float*)(ws + 65536 + 2097152 + 32768);              // 32 KiB

    hipLaunchKernelGGL(k_wt,   dim3(128), dim3(256), 0, stream, W, WT);
    hipLaunchKernelGGL(k_wh,   dim3(128), dim3(256), 0, stream, h, a, WT, WhT, s1, s2);
    hipLaunchKernelGGL(k_attn, dim3(512), dim3(256), 0, stream, adj, WhT, s1, s2, gamma, beta, out);
}